// Round 1
// baseline (52.675 us; speedup 1.0000x reference)
//
#include <hip/hip_runtime.h>
#include <math.h>

#define NBATCH  4096
#define NFIELDS 24
#define EMBED   32
#define NVOCAB  96000
#define NPAIRS  ((NFIELDS * (NFIELDS - 1)) / 2)   // 276

// One block per batch sample. 256 threads = 32 groups of 8 lanes.
// Each 8-lane group handles one (i,j) pair per iteration:
//   lane k loads float4 of ffm_W[i, id_j, 4k..4k+3] and ffm_W[j, id_i, 4k..4k+3]
//   -> two perfectly coalesced 128B-line reads per pair.
// Per-thread partial sums are block-reduced; linear term is folded in by
// threads 0..23 seeding their partial with fc_W[id_f].
__global__ __launch_bounds__(256) void ffm_fwd_kernel(
    const int* __restrict__ x,          // [NBATCH, NFIELDS] int32
    const int* __restrict__ offsets,    // [NFIELDS] int32
    const float* __restrict__ ffm_W,    // [NFIELDS, NVOCAB, EMBED] f32
    const float* __restrict__ fc_W,     // [NVOCAB, 1] f32
    const float* __restrict__ bias,     // [1] f32
    float* __restrict__ out)            // [NBATCH] f32
{
    const int b   = blockIdx.x;
    const int tid = threadIdx.x;

    __shared__ int           s_ids[NFIELDS];
    __shared__ unsigned char s_pi[NPAIRS];
    __shared__ unsigned char s_pj[NPAIRS];
    __shared__ float         s_wsum[4];

    // Build the pair (i<j) lookup table in parallel (trip count <= 2).
    for (int p = tid; p < NPAIRS; p += 256) {
        int i = 0, rem = p;
        while (rem >= NFIELDS - 1 - i) { rem -= NFIELDS - 1 - i; ++i; }
        s_pi[p] = (unsigned char)i;
        s_pj[p] = (unsigned char)(i + 1 + rem);
    }

    float local = 0.0f;
    if (tid < NFIELDS) {
        const int id = x[b * NFIELDS + tid] + offsets[tid];
        s_ids[tid] = id;
        local = fc_W[id];   // linear term, folded into the block reduction
    }
    __syncthreads();

    const int group = tid >> 3;   // 0..31
    const int lane8 = tid & 7;    // 0..7

    // 276 pairs / 32 groups: 8 full rounds + tail (groups 0..19).
    #pragma unroll
    for (int it = 0; it < 8; ++it) {
        const int p = group + it * 32;
        const int i = s_pi[p];
        const int j = s_pj[p];
        const float4 av = *(const float4*)(ffm_W +
            ((long long)i * NVOCAB + s_ids[j]) * EMBED + lane8 * 4);
        const float4 bv = *(const float4*)(ffm_W +
            ((long long)j * NVOCAB + s_ids[i]) * EMBED + lane8 * 4);
        local += av.x * bv.x + av.y * bv.y + av.z * bv.z + av.w * bv.w;
    }
    {
        const int p = group + 256;
        if (p < NPAIRS) {
            const int i = s_pi[p];
            const int j = s_pj[p];
            const float4 av = *(const float4*)(ffm_W +
                ((long long)i * NVOCAB + s_ids[j]) * EMBED + lane8 * 4);
            const float4 bv = *(const float4*)(ffm_W +
                ((long long)j * NVOCAB + s_ids[i]) * EMBED + lane8 * 4);
            local += av.x * bv.x + av.y * bv.y + av.z * bv.z + av.w * bv.w;
        }
    }

    // Block reduction: wave64 shuffle tree, then cross-wave via LDS.
    #pragma unroll
    for (int off = 32; off > 0; off >>= 1)
        local += __shfl_xor(local, off);
    if ((tid & 63) == 0) s_wsum[tid >> 6] = local;
    __syncthreads();
    if (tid == 0) {
        const float z = s_wsum[0] + s_wsum[1] + s_wsum[2] + s_wsum[3] + bias[0];
        out[b] = 1.0f / (1.0f + __expf(-z));
    }
}

extern "C" void kernel_launch(void* const* d_in, const int* in_sizes, int n_in,
                              void* d_out, int out_size, void* d_ws, size_t ws_size,
                              hipStream_t stream) {
    const int*   x       = (const int*)d_in[0];
    const int*   offsets = (const int*)d_in[1];
    const float* ffm_W   = (const float*)d_in[2];
    const float* fc_W    = (const float*)d_in[3];
    const float* bias    = (const float*)d_in[4];
    float*       out     = (float*)d_out;

    ffm_fwd_kernel<<<NBATCH, 256, 0, stream>>>(x, offsets, ffm_W, fc_W, bias, out);
}

// Round 2
// 52.117 us; speedup vs baseline: 1.0107x; 1.0107x over previous
//
#include <hip/hip_runtime.h>
#include <math.h>

#define NBATCH  4096
#define NFIELDS 24
#define EMBED   32
#define NVOCAB  96000
#define NPAIRS  ((NFIELDS * (NFIELDS - 1)) / 2)   // 276

#define CHUNKS        64                 // blocks per pair
#define SAMP_PER_BLK  (NBATCH / CHUNKS)  // 64 samples per block
#define PAIRS_MAIN    34                 // pairs per XCD in the main region (34*8 = 272)

// ---------------- Pass 1: pair-major cross-term dots ----------------
// grid = NPAIRS * CHUNKS blocks, 256 threads.
// XCD pinning: hardware assigns block -> XCD as (blockIdx.x % 8). We decode
// (pair, chunk) from (xcd, ordinal) so that all 64 chunk-blocks of a pair run
// on ONE XCD => the pair's two 512KB ffm_W slices stay L2-resident and the
// ~1.6x id-collision reuse is served by L2 instead of MALL/HBM.
__global__ __launch_bounds__(256) void ffm_pairs_kernel(
    const int* __restrict__ x,          // [NBATCH, NFIELDS]
    const int* __restrict__ offsets,    // [NFIELDS]
    const float* __restrict__ ffm_W,    // [NFIELDS, NVOCAB, EMBED]
    float* __restrict__ part)           // [NPAIRS, NBATCH]
{
    const int tid = threadIdx.x;
    const int x8  = blockIdx.x & 7;     // XCD id (hw round-robin heuristic)
    const int o   = blockIdx.x >> 3;    // ordinal within this XCD

    int pair, chunk;
    const int pl = o / CHUNKS;
    if (pl < PAIRS_MAIN) {              // pairs 0..271: 34 pairs per XCD
        pair  = pl * 8 + x8;
        chunk = o - pl * CHUNKS;
    } else {                            // pairs 272..275: 2 XCDs share a pair
        const int r = (o - PAIRS_MAIN * CHUNKS) + x8 * (CHUNKS / 2);
        pair  = 272 + (r >> 6);
        chunk = r & (CHUNKS - 1);
    }

    // decode pair -> (i < j)
    int i = 0, rem = pair;
    while (rem >= NFIELDS - 1 - i) { rem -= NFIELDS - 1 - i; ++i; }
    const int j = i + 1 + rem;

    const int b0 = chunk * SAMP_PER_BLK;

    __shared__ int s_aid[SAMP_PER_BLK];  // id into table i  (= x[b,j] + off_j)
    __shared__ int s_bid[SAMP_PER_BLK];  // id into table j  (= x[b,i] + off_i)

    if (tid < SAMP_PER_BLK) {
        s_bid[tid] = x[(b0 + tid) * NFIELDS + i] + offsets[i];
    } else if (tid < 2 * SAMP_PER_BLK) {
        const int t = tid - SAMP_PER_BLK;
        s_aid[t] = x[(b0 + t) * NFIELDS + j] + offsets[j];
    }
    __syncthreads();

    const int g  = tid >> 3;            // 0..31 : sample group
    const int l4 = (tid & 7) * 4;       // float4 offset within embedding

    #pragma unroll
    for (int k = 0; k < SAMP_PER_BLK / 32; ++k) {
        const int bl = k * 32 + g;
        const float4 av = *(const float4*)(ffm_W +
            ((long long)i * NVOCAB + s_aid[bl]) * EMBED + l4);
        const float4 bv = *(const float4*)(ffm_W +
            ((long long)j * NVOCAB + s_bid[bl]) * EMBED + l4);
        float d = av.x * bv.x + av.y * bv.y + av.z * bv.z + av.w * bv.w;
        d += __shfl_xor(d, 1);
        d += __shfl_xor(d, 2);
        d += __shfl_xor(d, 4);
        if ((tid & 7) == 0)
            part[(long long)pair * NBATCH + b0 + bl] = d;
    }
}

// ---------------- Pass 2: reduce pairs + linear term + sigmoid ----------------
__global__ __launch_bounds__(256) void ffm_finalize_kernel(
    const int* __restrict__ x,
    const int* __restrict__ offsets,
    const float* __restrict__ fc_W,     // [NVOCAB, 1]
    const float* __restrict__ bias,     // [1]
    const float* __restrict__ part,     // [NPAIRS, NBATCH]
    float* __restrict__ out)            // [NBATCH]
{
    const int b = blockIdx.x * 256 + threadIdx.x;

    float lin = bias[0];
    #pragma unroll
    for (int f = 0; f < NFIELDS; ++f)
        lin += fc_W[x[b * NFIELDS + f] + offsets[f]];

    const float* pb = part + b;
    float s0 = 0.f, s1 = 0.f, s2 = 0.f, s3 = 0.f;
    #pragma unroll 4
    for (int p = 0; p < NPAIRS; p += 4) {
        s0 += pb[(long long)(p + 0) * NBATCH];
        s1 += pb[(long long)(p + 1) * NBATCH];
        s2 += pb[(long long)(p + 2) * NBATCH];
        s3 += pb[(long long)(p + 3) * NBATCH];
    }
    const float z = lin + ((s0 + s1) + (s2 + s3));
    out[b] = 1.0f / (1.0f + __expf(-z));
}

extern "C" void kernel_launch(void* const* d_in, const int* in_sizes, int n_in,
                              void* d_out, int out_size, void* d_ws, size_t ws_size,
                              hipStream_t stream) {
    const int*   x       = (const int*)d_in[0];
    const int*   offsets = (const int*)d_in[1];
    const float* ffm_W   = (const float*)d_in[2];
    const float* fc_W    = (const float*)d_in[3];
    const float* bias    = (const float*)d_in[4];
    float*       out     = (float*)d_out;
    float*       part    = (float*)d_ws;   // NPAIRS*NBATCH floats = 4.5 MB

    ffm_pairs_kernel<<<NPAIRS * CHUNKS, 256, 0, stream>>>(x, offsets, ffm_W, part);
    ffm_finalize_kernel<<<NBATCH / 256, 256, 0, stream>>>(x, offsets, fc_W, bias, part, out);
}